// Round 3
// baseline (479.409 us; speedup 1.0000x reference)
//
#include <hip/hip_runtime.h>

#define B_SZ 4
#define SEQ  4096
#define DM   1024
#define DSTATE 16
#define ROWS (B_SZ*SEQ)   // 16384

typedef unsigned short u16;
typedef __attribute__((ext_vector_type(8))) short   s16x8;   // 8 bf16 (4 VGPRs)
typedef __attribute__((ext_vector_type(4))) float   f32x4;
typedef __attribute__((ext_vector_type(4))) u16     u16x4;

__device__ inline float bf2f(u16 u) {
    unsigned v = ((unsigned)u) << 16;
    float f; __builtin_memcpy(&f, &v, 4); return f;
}
__device__ inline u16 f2bf(float f) {
    unsigned u; __builtin_memcpy(&u, &f, 4);
    return (u16)((u + 0x7FFFu + ((u >> 16) & 1u)) >> 16);   // RNE
}
__device__ inline f32x4 mfma16(s16x8 a, s16x8 b, f32x4 c) {
    return __builtin_amdgcn_mfma_f32_16x16x32_bf16(a, b, c, 0, 0, 0);
}

// ---------------------------------------------------------------------------
// K0a: x fp32 -> (xh, xl) bf16 split.  x = xh + xl + O(2^-18 |x|)
// ---------------------------------------------------------------------------
__global__ __launch_bounds__(256) void k_cvt_split(
    const float* __restrict__ in, u16* __restrict__ oh, u16* __restrict__ ol, int n4)
{
    int i = blockIdx.x * 256 + threadIdx.x;
    if (i < n4) {
        f32x4 v = ((const f32x4*)in)[i];
        u16x4 h, l;
#pragma unroll
        for (int c = 0; c < 4; c++) {
            h[c] = f2bf(v[c]);
            l[c] = f2bf(v[c] - bf2f(h[c]));
        }
        ((u16x4*)oh)[i] = h;
        ((u16x4*)ol)[i] = l;
    }
}

// K0b: fp32 -> bf16 (single) for gate_w
__global__ __launch_bounds__(256) void k_cvt(
    const float* __restrict__ in, u16* __restrict__ out, int n4)
{
    int i = blockIdx.x * 256 + threadIdx.x;
    if (i < n4) {
        f32x4 v = ((const f32x4*)in)[i];
        u16x4 o;
#pragma unroll
        for (int c = 0; c < 4; c++) o[c] = f2bf(v[c]);
        ((u16x4*)out)[i] = o;
    }
}

// ---------------------------------------------------------------------------
// K1: Bx/Cx = x @ B_w^T, x @ C_w^T with 3-pass split-bf16 MFMA (fp32-grade):
// xh*wh + xl*wh + xh*wl.  One wave -> 64 rows x 16 cols for both B and C.
// A-frag: A[m=lane&15][k=8*(lane>>4)+j]; B-frag: B[k][n=lane&15] (W^T form).
// D: row = 4*(lane>>4)+r, col = lane&15.
// ---------------------------------------------------------------------------
__global__ __launch_bounds__(256) void k_bxcx(
    const u16* __restrict__ xh, const u16* __restrict__ xl,
    const float* __restrict__ Bw, const float* __restrict__ Cw,
    float* __restrict__ Bx, float* __restrict__ Cx)
{
    int wave = (blockIdx.x * 256 + threadIdx.x) >> 6;
    int lane = threadIdx.x & 63;
    int lo = lane & 15, hi = lane >> 4;
    int m0 = wave * 64;
    f32x4 accB[4] = {}, accC[4] = {};
    for (int k0 = 0; k0 < DM; k0 += 32) {
        const float* bp = Bw + (size_t)lo * DM + k0 + hi * 8;
        const float* cp = Cw + (size_t)lo * DM + k0 + hi * 8;
        f32x4 b0 = *(const f32x4*)bp, b1 = *(const f32x4*)(bp + 4);
        f32x4 c0 = *(const f32x4*)cp, c1 = *(const f32x4*)(cp + 4);
        s16x8 bh, bl, ch, cl;
#pragma unroll
        for (int c = 0; c < 4; c++) {
            u16 t;
            t = f2bf(b0[c]); bh[c] = (short)t;     bl[c]     = (short)f2bf(b0[c] - bf2f(t));
            t = f2bf(b1[c]); bh[c + 4] = (short)t; bl[c + 4] = (short)f2bf(b1[c] - bf2f(t));
            t = f2bf(c0[c]); ch[c] = (short)t;     cl[c]     = (short)f2bf(c0[c] - bf2f(t));
            t = f2bf(c1[c]); ch[c + 4] = (short)t; cl[c + 4] = (short)f2bf(c1[c] - bf2f(t));
        }
#pragma unroll
        for (int mt = 0; mt < 4; mt++) {
            size_t off = (size_t)(m0 + mt * 16 + lo) * DM + k0 + hi * 8;
            s16x8 ah = *(const s16x8*)(xh + off);
            s16x8 al = *(const s16x8*)(xl + off);
            accB[mt] = mfma16(ah, bh, accB[mt]);
            accB[mt] = mfma16(al, bh, accB[mt]);
            accB[mt] = mfma16(ah, bl, accB[mt]);
            accC[mt] = mfma16(ah, ch, accC[mt]);
            accC[mt] = mfma16(al, ch, accC[mt]);
            accC[mt] = mfma16(ah, cl, accC[mt]);
        }
    }
#pragma unroll
    for (int mt = 0; mt < 4; mt++)
#pragma unroll
        for (int r = 0; r < 4; r++) {
            int m = m0 + mt * 16 + hi * 4 + r;
            Bx[(size_t)m * DSTATE + lo] = accB[mt][r];
            Cx[(size_t)m * DSTATE + lo] = accC[mt][r];
        }
}

// ---------------------------------------------------------------------------
// K2: gate = sigmoid(x @ gate_w^T + gate_b), fp32 out (into d_out buffer).
// 2-pass split on x (xh*wh + xl*wh); W single bf16.
// Block = 4 waves in 2x2 -> 128x128 tile; wave tile 64x64 (4x4 MFMA).
// ---------------------------------------------------------------------------
__global__ __launch_bounds__(256) void k_gate(
    const u16* __restrict__ xh, const u16* __restrict__ xl,
    const u16* __restrict__ gwb, const float* __restrict__ gb,
    float* __restrict__ gate)
{
    int wv = threadIdx.x >> 6, lane = threadIdx.x & 63;
    int lo = lane & 15, hi = lane >> 4;
    int m0 = blockIdx.x * 128 + (wv & 1) * 64;
    int n0 = blockIdx.y * 128 + (wv >> 1) * 64;
    const u16* ah_p = xh  + (size_t)m0 * DM;
    const u16* al_p = xl  + (size_t)m0 * DM;
    const u16* bptr = gwb + (size_t)n0 * DM;
    f32x4 acc[4][4] = {};
    for (int k0 = 0; k0 < DM; k0 += 32) {
        s16x8 ah[4], al[4], b[4];
#pragma unroll
        for (int i = 0; i < 4; i++) {
            size_t off = (size_t)(i * 16 + lo) * DM + k0 + hi * 8;
            ah[i] = *(const s16x8*)(ah_p + off);
            al[i] = *(const s16x8*)(al_p + off);
        }
#pragma unroll
        for (int j = 0; j < 4; j++)
            b[j] = *(const s16x8*)(bptr + (size_t)(j * 16 + lo) * DM + k0 + hi * 8);
#pragma unroll
        for (int i = 0; i < 4; i++)
#pragma unroll
            for (int j = 0; j < 4; j++) {
                acc[i][j] = mfma16(ah[i], b[j], acc[i][j]);
                acc[i][j] = mfma16(al[i], b[j], acc[i][j]);
            }
    }
#pragma unroll
    for (int i = 0; i < 4; i++)
#pragma unroll
        for (int r = 0; r < 4; r++) {
            int m = m0 + i * 16 + hi * 4 + r;
#pragma unroll
            for (int j = 0; j < 4; j++) {
                int n = n0 + j * 16 + lo;
                float v = acc[i][j][r] + gb[n];
                gate[(size_t)m * DM + n] = 1.0f / (1.0f + __expf(-v));
            }
        }
}

// ---------------------------------------------------------------------------
// K3: windowed scan. A = exp(A_log) <= e^-1, so 32-step lookback truncation
// error <= 1.3e-14. Thread = one (b,d) channel over one chunk. All fp32.
// gate_out: read gate (fp32), overwrite with out_pre in place (same element,
// same thread, read-before-write; deliberately NOT __restrict__).
// ---------------------------------------------------------------------------
#define CHUNK_L 128
#define LOOKBACK 32

__global__ __launch_bounds__(256) void k_scan(
    const float* __restrict__ x, const float* __restrict__ A_log,
    const float* __restrict__ Bx, const float* __restrict__ Cx,
    const float* __restrict__ Dvec, float* gate_out)
{
    int d = blockIdx.x * 256 + threadIdx.x;   // 0..1023
    int b = blockIdx.z;
    int t0 = blockIdx.y * CHUNK_L;

    float A[DSTATE], h[DSTATE];
#pragma unroll
    for (int n = 0; n < DSTATE; n++) {
        A[n] = expf(A_log[(size_t)d * DSTATE + n]);
        h[n] = 0.0f;
    }
    float Dd = Dvec[d];

    int tstart = t0 - LOOKBACK; if (tstart < 0) tstart = 0;
    for (int t = tstart; t < t0 + CHUNK_L; ++t) {
        size_t rb = (size_t)(b * SEQ + t);
        float xv = x[rb * DM + d];
        const f32x4* bxp = (const f32x4*)(Bx + rb * DSTATE);
        const f32x4* cxp = (const f32x4*)(Cx + rb * DSTATE);
        f32x4 bx[4], cx[4];
#pragma unroll
        for (int q = 0; q < 4; q++) { bx[q] = bxp[q]; cx[q] = cxp[q]; }
        float y = 0.0f;
#pragma unroll
        for (int n = 0; n < DSTATE; n++) {
            h[n] = h[n] * A[n] + bx[n >> 2][n & 3] * xv;
            y += h[n] * cx[n >> 2][n & 3];
        }
        if (t >= t0) {
            float g  = gate_out[rb * DM + d];
            float yv = y + Dd * xv;
            gate_out[rb * DM + d] = g * yv + (1.0f - g) * xv;
        }
    }
}

// ---------------------------------------------------------------------------
// K4: LayerNorm over last dim (1024), fp32, IN PLACE on d_out.
// One wave per row; each thread loads its 16 elems before any store.
// ---------------------------------------------------------------------------
__global__ __launch_bounds__(256) void k_ln(
    float* data, const float* __restrict__ gamma, const float* __restrict__ beta)
{
    int wv = threadIdx.x >> 6, lane = threadIdx.x & 63;
    int row = blockIdx.x * 4 + wv;
    f32x4* rp = (f32x4*)(data + (size_t)row * DM);
    f32x4 v[4];
#pragma unroll
    for (int j = 0; j < 4; j++) v[j] = rp[lane + 64 * j];
    float s = 0.0f, s2 = 0.0f;
#pragma unroll
    for (int j = 0; j < 4; j++)
#pragma unroll
        for (int c = 0; c < 4; c++) { float t = v[j][c]; s += t; s2 += t * t; }
#pragma unroll
    for (int off = 32; off > 0; off >>= 1) {
        s  += __shfl_down(s,  off);
        s2 += __shfl_down(s2, off);
    }
    s = __shfl(s, 0); s2 = __shfl(s2, 0);
    float mu  = s  * (1.0f / DM);
    float var = s2 * (1.0f / DM) - mu * mu;
    float rs  = rsqrtf(var + 1e-5f);
#pragma unroll
    for (int j = 0; j < 4; j++) {
        int c0 = (lane + 64 * j) * 4;
        f32x4 o;
#pragma unroll
        for (int c = 0; c < 4; c++)
            o[c] = (v[j][c] - mu) * rs * gamma[c0 + c] + beta[c0 + c];
        rp[lane + 64 * j] = o;
    }
}

// ---------------------------------------------------------------------------
extern "C" void kernel_launch(void* const* d_in, const int* in_sizes, int n_in,
                              void* d_out, int out_size, void* d_ws, size_t ws_size,
                              hipStream_t stream)
{
    const float* x     = (const float*)d_in[0];
    const float* A_log = (const float*)d_in[1];
    const float* Bw    = (const float*)d_in[2];
    const float* Cw    = (const float*)d_in[3];
    const float* Dv    = (const float*)d_in[4];
    const float* gw    = (const float*)d_in[5];
    const float* gb    = (const float*)d_in[6];
    const float* gam   = (const float*)d_in[7];
    const float* bet   = (const float*)d_in[8];
    float* out = (float*)d_out;   // reused as: gate (fp32) -> out_pre -> final

    char* ws = (char*)d_ws;
    u16*   xh  = (u16*)  ws;                       // 32 MB
    u16*   xl  = (u16*)  (ws + (32u << 20));       // 32 MB
    u16*   gwb = (u16*)  (ws + (64u << 20));       // 2 MB
    float* Bx  = (float*)(ws + (66u << 20));       // 1 MB
    float* Cx  = (float*)(ws + (67u << 20));       // 1 MB

    k_cvt_split<<<ROWS * DM / 4 / 256, 256, 0, stream>>>(x, xh, xl, ROWS * DM / 4);
    k_cvt<<<DM * DM / 4 / 256, 256, 0, stream>>>(gw, gwb, DM * DM / 4);
    k_bxcx<<<ROWS / 64 / 4, 256, 0, stream>>>(xh, xl, Bw, Cw, Bx, Cx);
    k_gate<<<dim3(ROWS / 128, DM / 128), 256, 0, stream>>>(xh, xl, gwb, gb, out);
    k_scan<<<dim3(DM / 256, SEQ / CHUNK_L, B_SZ), 256, 0, stream>>>(
        x, A_log, Bx, Cx, Dv, out);
    k_ln<<<ROWS / 4, 256, 0, stream>>>(out, gam, bet);
}

// Round 4
// 316.284 us; speedup vs baseline: 1.5158x; 1.5158x over previous
//
#include <hip/hip_runtime.h>

#define B_SZ 4
#define SEQ  4096
#define DM   1024
#define DSTATE 16
#define ROWS (B_SZ*SEQ)   // 16384

typedef unsigned short u16;
typedef __attribute__((ext_vector_type(8))) short   s16x8;   // 8 bf16 (4 VGPRs)
typedef __attribute__((ext_vector_type(4))) float   f32x4;
typedef __attribute__((ext_vector_type(4))) u16     u16x4;

__device__ inline float bf2f(u16 u) {
    unsigned v = ((unsigned)u) << 16;
    float f; __builtin_memcpy(&f, &v, 4); return f;
}
__device__ inline u16 f2bf(float f) {
    unsigned u; __builtin_memcpy(&u, &f, 4);
    return (u16)((u + 0x7FFFu + ((u >> 16) & 1u)) >> 16);   // RNE
}
__device__ inline f32x4 mfma16(s16x8 a, s16x8 b, f32x4 c) {
    return __builtin_amdgcn_mfma_f32_16x16x32_bf16(a, b, c, 0, 0, 0);
}
// async global->LDS, 16B per lane, dest = wave-uniform base + lane*16
__device__ inline void gl_lds16(const u16* g, u16* l) {
    __builtin_amdgcn_global_load_lds(
        (const __attribute__((address_space(1))) unsigned int*)g,
        (__attribute__((address_space(3))) unsigned int*)l, 16, 0, 0);
}

// ---------------------------------------------------------------------------
// K0a: x fp32 -> (xh, xl) bf16 split.  x = xh + xl + O(2^-18 |x|)
// ---------------------------------------------------------------------------
__global__ __launch_bounds__(256) void k_cvt_split(
    const float* __restrict__ in, u16* __restrict__ oh, u16* __restrict__ ol, int n4)
{
    int i = blockIdx.x * 256 + threadIdx.x;
    if (i < n4) {
        f32x4 v = ((const f32x4*)in)[i];
        u16x4 h, l;
#pragma unroll
        for (int c = 0; c < 4; c++) {
            h[c] = f2bf(v[c]);
            l[c] = f2bf(v[c] - bf2f(h[c]));
        }
        ((u16x4*)oh)[i] = h;
        ((u16x4*)ol)[i] = l;
    }
}

// ---------------------------------------------------------------------------
// K0b: weight conversions in one launch.
// blocks [0,1024): gw -> gwb (bf16).  [1024,1040): Bw -> bwh/bwl split.
// [1040,1056): Cw -> cwh/cwl split.
// ---------------------------------------------------------------------------
__global__ __launch_bounds__(256) void k_cvt_w(
    const float* __restrict__ gw, const float* __restrict__ Bw,
    const float* __restrict__ Cw, u16* __restrict__ gwb,
    u16* __restrict__ bwh, u16* __restrict__ bwl,
    u16* __restrict__ cwh, u16* __restrict__ cwl)
{
    int blk = blockIdx.x;
    if (blk < 1024) {
        int i = blk * 256 + threadIdx.x;               // 262144 vec4 total
        f32x4 v = ((const f32x4*)gw)[i];
        u16x4 o;
#pragma unroll
        for (int c = 0; c < 4; c++) o[c] = f2bf(v[c]);
        ((u16x4*)gwb)[i] = o;
    } else {
        int isC = (blk >= 1040);
        const float* src = isC ? Cw : Bw;
        u16* dh = isC ? cwh : bwh;
        u16* dl = isC ? cwl : bwl;
        int i = (blk - (isC ? 1040 : 1024)) * 256 + threadIdx.x;   // 4096 vec4
        f32x4 v = ((const f32x4*)src)[i];
        u16x4 h, l;
#pragma unroll
        for (int c = 0; c < 4; c++) {
            h[c] = f2bf(v[c]);
            l[c] = f2bf(v[c] - bf2f(h[c]));
        }
        ((u16x4*)dh)[i] = h;
        ((u16x4*)dl)[i] = l;
    }
}

// ---------------------------------------------------------------------------
// K1: Bx/Cx = x @ B_w^T, x @ C_w^T, 3-pass split-bf16 MFMA (fp32-grade).
// One wave per 16-row M-tile -> 1024 single-wave blocks (full CU coverage).
// Weights pre-split to bf16 in ws (bwh/bwl/cwh/cwl), ~128 KB, L2-resident.
// ---------------------------------------------------------------------------
__global__ __launch_bounds__(64) void k_bxcx(
    const u16* __restrict__ xh, const u16* __restrict__ xl,
    const u16* __restrict__ bwh, const u16* __restrict__ bwl,
    const u16* __restrict__ cwh, const u16* __restrict__ cwl,
    float* __restrict__ Bx, float* __restrict__ Cx)
{
    int lane = threadIdx.x;
    int lo = lane & 15, hi = lane >> 4;
    int m0 = blockIdx.x * 16;
    f32x4 accB = {}, accC = {};
    for (int k0 = 0; k0 < DM; k0 += 32) {
        size_t woff = (size_t)lo * DM + k0 + hi * 8;
        s16x8 bh = *(const s16x8*)(bwh + woff);
        s16x8 bl = *(const s16x8*)(bwl + woff);
        s16x8 ch = *(const s16x8*)(cwh + woff);
        s16x8 cl = *(const s16x8*)(cwl + woff);
        size_t aoff = (size_t)(m0 + lo) * DM + k0 + hi * 8;
        s16x8 ah = *(const s16x8*)(xh + aoff);
        s16x8 al = *(const s16x8*)(xl + aoff);
        accB = mfma16(ah, bh, accB);
        accB = mfma16(al, bh, accB);
        accB = mfma16(ah, bl, accB);
        accC = mfma16(ah, ch, accC);
        accC = mfma16(al, ch, accC);
        accC = mfma16(ah, cl, accC);
    }
#pragma unroll
    for (int r = 0; r < 4; r++) {
        int m = m0 + hi * 4 + r;
        Bx[(size_t)m * DSTATE + lo] = accB[r];
        Cx[(size_t)m * DSTATE + lo] = accC[r];
    }
}

// ---------------------------------------------------------------------------
// K2: gate = sigmoid(x @ gate_w^T + gate_b), fp32 out (into d_out).
// m97-structure: 128x128 tile, BK=64, LDS staging via global_load_lds w=16.
// XOR swizzle on 16B chunks (p = c ^ (r&7)) -> conflict-free ds_read_b128
// while satisfying the wave-uniform-base staging layout.
// 2-pass split on x (xh*wh + xl*wh); W single bf16.
// ---------------------------------------------------------------------------
#define BM 128
#define BN 128
#define BK 64

__global__ __launch_bounds__(256) void k_gate(
    const u16* __restrict__ xh, const u16* __restrict__ xl,
    const u16* __restrict__ gwb, const float* __restrict__ gb,
    float* __restrict__ gate)
{
    __shared__ u16 sAh[BM * BK], sAl[BM * BK], sB[BN * BK];
    int tid = threadIdx.x;
    int wv = tid >> 6, lane = tid & 63;
    int lo = lane & 15, hi = lane >> 4;
    int m0 = blockIdx.x * BM;
    int n0 = blockIdx.y * BN;

    int r_in = lane >> 3;          // row within 1KB staging issue (8 rows)
    int p    = lane & 7;           // physical 16B chunk slot in LDS row
    int c    = p ^ r_in;           // swizzled source chunk (r&7 == r_in here)

    int mrow = (wv & 1) * 64;      // wave's rows within BM
    int ncol = (wv >> 1) * 64;     // wave's cols within BN

    f32x4 acc[4][4] = {};
    for (int k0 = 0; k0 < DM; k0 += BK) {
        __syncthreads();
#pragma unroll
        for (int q = 0; q < 4; q++) {
            int r = (wv * 4 + q) * 8 + r_in;            // 0..127
            size_t goff = (size_t)r * DM + k0 + c * 8;
            gl_lds16(xh  + (size_t)m0 * DM + goff, &sAh[(wv * 4 + q) * 512]);
            gl_lds16(xl  + (size_t)m0 * DM + goff, &sAl[(wv * 4 + q) * 512]);
            gl_lds16(gwb + (size_t)n0 * DM + goff, &sB [(wv * 4 + q) * 512]);
        }
        __syncthreads();
#pragma unroll
        for (int kk = 0; kk < 2; kk++) {
            s16x8 bfr[4], ah[4], al[4];
#pragma unroll
            for (int j = 0; j < 4; j++) {
                int rb = ncol + j * 16 + lo;
                int pc = (kk * 4 + hi) ^ (rb & 7);
                bfr[j] = *(const s16x8*)&sB[rb * BK + pc * 8];
            }
#pragma unroll
            for (int i = 0; i < 4; i++) {
                int ra = mrow + i * 16 + lo;
                int pc = (kk * 4 + hi) ^ (ra & 7);
                ah[i] = *(const s16x8*)&sAh[ra * BK + pc * 8];
                al[i] = *(const s16x8*)&sAl[ra * BK + pc * 8];
            }
#pragma unroll
            for (int i = 0; i < 4; i++)
#pragma unroll
                for (int j = 0; j < 4; j++) {
                    acc[i][j] = mfma16(ah[i], bfr[j], acc[i][j]);
                    acc[i][j] = mfma16(al[i], bfr[j], acc[i][j]);
                }
        }
    }
#pragma unroll
    for (int i = 0; i < 4; i++)
#pragma unroll
        for (int r = 0; r < 4; r++) {
            int m = m0 + mrow + i * 16 + hi * 4 + r;
#pragma unroll
            for (int j = 0; j < 4; j++) {
                int n = n0 + ncol + j * 16 + lo;
                float v = acc[i][j][r] + gb[n];
                gate[(size_t)m * DM + n] = 1.0f / (1.0f + __expf(-v));
            }
        }
}

// ---------------------------------------------------------------------------
// K3: windowed scan, Bx/Cx staged in LDS (broadcast reads).
// A = exp(A_log) <= e^-1 -> 32-step lookback truncation <= 1.3e-14.
// Thread = one (b,d) channel over one 64-step chunk. All fp32.
// gate_out read-then-overwritten in place (same elem, same thread).
// ---------------------------------------------------------------------------
#define CHUNK_L 64
#define LOOKBACK 32

__global__ __launch_bounds__(256) void k_scan(
    const float* __restrict__ x, const float* __restrict__ A_log,
    const float* __restrict__ Bx, const float* __restrict__ Cx,
    const float* __restrict__ Dvec, float* gate_out)
{
    __shared__ float sBx[(CHUNK_L + LOOKBACK) * DSTATE];   // 6 KB
    __shared__ float sCx[(CHUNK_L + LOOKBACK) * DSTATE];   // 6 KB
    int d = blockIdx.x * 256 + threadIdx.x;   // 0..1023
    int b = blockIdx.z;
    int t0 = blockIdx.y * CHUNK_L;
    int tstart = t0 - LOOKBACK; if (tstart < 0) tstart = 0;
    int nrow = t0 + CHUNK_L - tstart;         // 64 or 96
    int nv = nrow * (DSTATE / 4);

    const f32x4* gB = (const f32x4*)(Bx + ((size_t)b * SEQ + tstart) * DSTATE);
    const f32x4* gC = (const f32x4*)(Cx + ((size_t)b * SEQ + tstart) * DSTATE);
    for (int i = threadIdx.x; i < nv; i += 256) {
        ((f32x4*)sBx)[i] = gB[i];
        ((f32x4*)sCx)[i] = gC[i];
    }

    float A[DSTATE], h[DSTATE];
    const f32x4* ga = (const f32x4*)(A_log + (size_t)d * DSTATE);
#pragma unroll
    for (int q = 0; q < 4; q++) {
        f32x4 av = ga[q];
#pragma unroll
        for (int c = 0; c < 4; c++) {
            A[q * 4 + c] = expf(av[c]);
            h[q * 4 + c] = 0.0f;
        }
    }
    float Dd = Dvec[d];
    __syncthreads();

    for (int t = tstart; t < t0 + CHUNK_L; ++t) {
        int idx = t - tstart;
        size_t rb = (size_t)(b * SEQ + t);
        float xv = x[rb * DM + d];
        f32x4 bx[4], cx[4];
#pragma unroll
        for (int q = 0; q < 4; q++) {
            bx[q] = ((const f32x4*)sBx)[idx * 4 + q];
            cx[q] = ((const f32x4*)sCx)[idx * 4 + q];
        }
        float y = 0.0f;
#pragma unroll
        for (int n = 0; n < DSTATE; n++) {
            h[n] = h[n] * A[n] + bx[n >> 2][n & 3] * xv;
            y += h[n] * cx[n >> 2][n & 3];
        }
        if (t >= t0) {
            float g  = gate_out[rb * DM + d];
            float yv = y + Dd * xv;
            gate_out[rb * DM + d] = g * yv + (1.0f - g) * xv;
        }
    }
}

// ---------------------------------------------------------------------------
// K4: LayerNorm over last dim (1024), fp32, IN PLACE on d_out.
// One wave per row; each thread loads its 16 elems before any store.
// ---------------------------------------------------------------------------
__global__ __launch_bounds__(256) void k_ln(
    float* data, const float* __restrict__ gamma, const float* __restrict__ beta)
{
    int wv = threadIdx.x >> 6, lane = threadIdx.x & 63;
    int row = blockIdx.x * 4 + wv;
    f32x4* rp = (f32x4*)(data + (size_t)row * DM);
    f32x4 v[4];
#pragma unroll
    for (int j = 0; j < 4; j++) v[j] = rp[lane + 64 * j];
    float s = 0.0f, s2 = 0.0f;
#pragma unroll
    for (int j = 0; j < 4; j++)
#pragma unroll
        for (int c = 0; c < 4; c++) { float t = v[j][c]; s += t; s2 += t * t; }
#pragma unroll
    for (int off = 32; off > 0; off >>= 1) {
        s  += __shfl_down(s,  off);
        s2 += __shfl_down(s2, off);
    }
    s = __shfl(s, 0); s2 = __shfl(s2, 0);
    float mu  = s  * (1.0f / DM);
    float var = s2 * (1.0f / DM) - mu * mu;
    float rs  = rsqrtf(var + 1e-5f);
#pragma unroll
    for (int j = 0; j < 4; j++) {
        int c0 = (lane + 64 * j) * 4;
        f32x4 o;
#pragma unroll
        for (int c = 0; c < 4; c++)
            o[c] = (v[j][c] - mu) * rs * gamma[c0 + c] + beta[c0 + c];
        rp[lane + 64 * j] = o;
    }
}

// ---------------------------------------------------------------------------
extern "C" void kernel_launch(void* const* d_in, const int* in_sizes, int n_in,
                              void* d_out, int out_size, void* d_ws, size_t ws_size,
                              hipStream_t stream)
{
    const float* x     = (const float*)d_in[0];
    const float* A_log = (const float*)d_in[1];
    const float* Bw    = (const float*)d_in[2];
    const float* Cw    = (const float*)d_in[3];
    const float* Dv    = (const float*)d_in[4];
    const float* gw    = (const float*)d_in[5];
    const float* gb    = (const float*)d_in[6];
    const float* gam   = (const float*)d_in[7];
    const float* bet   = (const float*)d_in[8];
    float* out = (float*)d_out;   // reused: gate (fp32) -> out_pre -> final

    char* ws = (char*)d_ws;
    u16*   xh  = (u16*)  ws;                             // 32 MB
    u16*   xl  = (u16*)  (ws + (32u << 20));             // 32 MB
    u16*   gwb = (u16*)  (ws + (64u << 20));             // 2 MB
    u16*   bwh = (u16*)  (ws + (66u << 20));             // 32 KB
    u16*   bwl = (u16*)  (ws + (66u << 20) + (32u << 10));
    u16*   cwh = (u16*)  (ws + (66u << 20) + (64u << 10));
    u16*   cwl = (u16*)  (ws + (66u << 20) + (96u << 10));
    float* Bx  = (float*)(ws + (67u << 20));             // 1 MB
    float* Cx  = (float*)(ws + (68u << 20));             // 1 MB

    k_cvt_split<<<ROWS * DM / 4 / 256, 256, 0, stream>>>(x, xh, xl, ROWS * DM / 4);
    k_cvt_w<<<1056, 256, 0, stream>>>(gw, Bw, Cw, gwb, bwh, bwl, cwh, cwl);
    k_bxcx<<<ROWS / 16, 64, 0, stream>>>(xh, xl, bwh, bwl, cwh, cwl, Bx, Cx);
    k_gate<<<dim3(ROWS / BM, DM / BN), 256, 0, stream>>>(xh, xl, gwb, gb, out);
    k_scan<<<dim3(DM / 256, SEQ / CHUNK_L, B_SZ), 256, 0, stream>>>(
        x, A_log, Bx, Cx, Dv, out);
    k_ln<<<ROWS / 4, 256, 0, stream>>>(out, gam, bet);
}

// Round 5
// 278.526 us; speedup vs baseline: 1.7212x; 1.1356x over previous
//
#include <hip/hip_runtime.h>

#define B_SZ 4
#define SEQ  4096
#define DM   1024
#define DSTATE 16
#define ROWS (B_SZ*SEQ)   // 16384

typedef unsigned short u16;
typedef __attribute__((ext_vector_type(8))) short   s16x8;   // 8 bf16 (4 VGPRs)
typedef __attribute__((ext_vector_type(4))) float   f32x4;
typedef __attribute__((ext_vector_type(4))) u16     u16x4;

__device__ inline float bf2f(u16 u) {
    unsigned v = ((unsigned)u) << 16;
    float f; __builtin_memcpy(&f, &v, 4); return f;
}
__device__ inline u16 f2bf(float f) {
    unsigned u; __builtin_memcpy(&u, &f, 4);
    return (u16)((u + 0x7FFFu + ((u >> 16) & 1u)) >> 16);   // RNE
}
__device__ inline f32x4 mfma16(s16x8 a, s16x8 b, f32x4 c) {
    return __builtin_amdgcn_mfma_f32_16x16x32_bf16(a, b, c, 0, 0, 0);
}
// async global->LDS, 16B per lane, dest = wave-uniform base + lane*16
__device__ inline void gl_lds16(const u16* g, u16* l) {
    __builtin_amdgcn_global_load_lds(
        (const __attribute__((address_space(1))) unsigned int*)g,
        (__attribute__((address_space(3))) unsigned int*)l, 16, 0, 0);
}

// ---------------------------------------------------------------------------
// K0a: x fp32 -> (xh, xl) bf16 split.  x = xh + xl + O(2^-18 |x|)
// (xl feeds only k_bxcx's 3-pass split — Bx/Cx precision is scan-amplified.)
// ---------------------------------------------------------------------------
__global__ __launch_bounds__(256) void k_cvt_split(
    const float* __restrict__ in, u16* __restrict__ oh, u16* __restrict__ ol, int n4)
{
    int i = blockIdx.x * 256 + threadIdx.x;
    if (i < n4) {
        f32x4 v = ((const f32x4*)in)[i];
        u16x4 h, l;
#pragma unroll
        for (int c = 0; c < 4; c++) {
            h[c] = f2bf(v[c]);
            l[c] = f2bf(v[c] - bf2f(h[c]));
        }
        ((u16x4*)oh)[i] = h;
        ((u16x4*)ol)[i] = l;
    }
}

// ---------------------------------------------------------------------------
// K0b: weight conversions in one launch.
// blocks [0,1024): gw -> gwb (bf16).  [1024,1040): Bw split. [1040,1056): Cw.
// ---------------------------------------------------------------------------
__global__ __launch_bounds__(256) void k_cvt_w(
    const float* __restrict__ gw, const float* __restrict__ Bw,
    const float* __restrict__ Cw, u16* __restrict__ gwb,
    u16* __restrict__ bwh, u16* __restrict__ bwl,
    u16* __restrict__ cwh, u16* __restrict__ cwl)
{
    int blk = blockIdx.x;
    if (blk < 1024) {
        int i = blk * 256 + threadIdx.x;
        f32x4 v = ((const f32x4*)gw)[i];
        u16x4 o;
#pragma unroll
        for (int c = 0; c < 4; c++) o[c] = f2bf(v[c]);
        ((u16x4*)gwb)[i] = o;
    } else {
        int isC = (blk >= 1040);
        const float* src = isC ? Cw : Bw;
        u16* dh = isC ? cwh : bwh;
        u16* dl = isC ? cwl : bwl;
        int i = (blk - (isC ? 1040 : 1024)) * 256 + threadIdx.x;
        f32x4 v = ((const f32x4*)src)[i];
        u16x4 h, l;
#pragma unroll
        for (int c = 0; c < 4; c++) {
            h[c] = f2bf(v[c]);
            l[c] = f2bf(v[c] - bf2f(h[c]));
        }
        ((u16x4*)dh)[i] = h;
        ((u16x4*)dl)[i] = l;
    }
}

// ---------------------------------------------------------------------------
// K1: Bx/Cx = x @ B_w^T, x @ C_w^T, 3-pass split-bf16 MFMA (fp32-grade).
// One wave per 16-row M-tile -> 1024 single-wave blocks.
// ---------------------------------------------------------------------------
__global__ __launch_bounds__(64) void k_bxcx(
    const u16* __restrict__ xh, const u16* __restrict__ xl,
    const u16* __restrict__ bwh, const u16* __restrict__ bwl,
    const u16* __restrict__ cwh, const u16* __restrict__ cwl,
    float* __restrict__ Bx, float* __restrict__ Cx)
{
    int lane = threadIdx.x;
    int lo = lane & 15, hi = lane >> 4;
    int m0 = blockIdx.x * 16;
    f32x4 accB = {}, accC = {};
    for (int k0 = 0; k0 < DM; k0 += 32) {
        size_t woff = (size_t)lo * DM + k0 + hi * 8;
        s16x8 bh = *(const s16x8*)(bwh + woff);
        s16x8 bl = *(const s16x8*)(bwl + woff);
        s16x8 ch = *(const s16x8*)(cwh + woff);
        s16x8 cl = *(const s16x8*)(cwl + woff);
        size_t aoff = (size_t)(m0 + lo) * DM + k0 + hi * 8;
        s16x8 ah = *(const s16x8*)(xh + aoff);
        s16x8 al = *(const s16x8*)(xl + aoff);
        accB = mfma16(ah, bh, accB);
        accB = mfma16(al, bh, accB);
        accB = mfma16(ah, bl, accB);
        accC = mfma16(ah, ch, accC);
        accC = mfma16(al, ch, accC);
        accC = mfma16(ah, cl, accC);
    }
#pragma unroll
    for (int r = 0; r < 4; r++) {
        int m = m0 + hi * 4 + r;
        Bx[(size_t)m * DSTATE + lo] = accB[r];
        Cx[(size_t)m * DSTATE + lo] = accC[r];
    }
}

// ---------------------------------------------------------------------------
// K2: gate = sigmoid(x @ gate_w^T + gate_b), fp32 out (into d_out).
// Single-pass bf16 (logit err ~0.002 -> dout <= ~0.06, within budget).
// 128x128 tile, BK=64, global_load_lds w=16, XOR-swizzled 16B chunks.
// ---------------------------------------------------------------------------
#define BM 128
#define BN 128
#define BK 64

__global__ __launch_bounds__(256) void k_gate(
    const u16* __restrict__ xh, const u16* __restrict__ gwb,
    const float* __restrict__ gb, float* __restrict__ gate)
{
    __shared__ u16 sA[BM * BK], sB[BN * BK];   // 16 KB + 16 KB
    int tid = threadIdx.x;
    int wv = tid >> 6, lane = tid & 63;
    int lo = lane & 15, hi = lane >> 4;
    int m0 = blockIdx.x * BM;
    int n0 = blockIdx.y * BN;

    int r_in = lane >> 3;          // row within 1KB staging issue (8 rows)
    int p    = lane & 7;           // physical 16B chunk slot in LDS row
    int c    = p ^ r_in;           // swizzled source chunk

    int mrow = (wv & 1) * 64;
    int ncol = (wv >> 1) * 64;

    f32x4 acc[4][4] = {};
    for (int k0 = 0; k0 < DM; k0 += BK) {
        __syncthreads();
#pragma unroll
        for (int q = 0; q < 4; q++) {
            int r = (wv * 4 + q) * 8 + r_in;            // 0..127
            size_t goff = (size_t)r * DM + k0 + c * 8;
            gl_lds16(xh  + (size_t)m0 * DM + goff, &sA[(wv * 4 + q) * 512]);
            gl_lds16(gwb + (size_t)n0 * DM + goff, &sB[(wv * 4 + q) * 512]);
        }
        __syncthreads();
#pragma unroll
        for (int kk = 0; kk < 2; kk++) {
            s16x8 bfr[4], afr[4];
#pragma unroll
            for (int j = 0; j < 4; j++) {
                int rb = ncol + j * 16 + lo;
                int pc = (kk * 4 + hi) ^ (rb & 7);
                bfr[j] = *(const s16x8*)&sB[rb * BK + pc * 8];
            }
#pragma unroll
            for (int i = 0; i < 4; i++) {
                int ra = mrow + i * 16 + lo;
                int pc = (kk * 4 + hi) ^ (ra & 7);
                afr[i] = *(const s16x8*)&sA[ra * BK + pc * 8];
            }
#pragma unroll
            for (int i = 0; i < 4; i++)
#pragma unroll
                for (int j = 0; j < 4; j++)
                    acc[i][j] = mfma16(afr[i], bfr[j], acc[i][j]);
        }
    }
#pragma unroll
    for (int i = 0; i < 4; i++)
#pragma unroll
        for (int r = 0; r < 4; r++) {
            int m = m0 + mrow + i * 16 + hi * 4 + r;
#pragma unroll
            for (int j = 0; j < 4; j++) {
                int n = n0 + ncol + j * 16 + lo;
                float v = acc[i][j][r] + gb[n];
                gate[(size_t)m * DM + n] = 1.0f / (1.0f + __expf(-v));
            }
        }
}

// ---------------------------------------------------------------------------
// K3: windowed scan, unroll-4 with batched loads for ILP.
// A = exp(A_log) <= e^-1 -> 32-step lookback truncation <= 1.3e-14.
// Thread = one (b,d) channel over one 64-step chunk. All fp32.
// gate_out read-then-overwritten in place (same elem, same thread).
// ---------------------------------------------------------------------------
#define CHUNK_L 64
#define LOOKBACK 32

__global__ __launch_bounds__(256) void k_scan(
    const float* __restrict__ x, const float* __restrict__ A_log,
    const float* __restrict__ Bx, const float* __restrict__ Cx,
    const float* __restrict__ Dvec, float* gate_out)
{
    __shared__ float sBx[(CHUNK_L + LOOKBACK) * DSTATE];   // 6 KB
    __shared__ float sCx[(CHUNK_L + LOOKBACK) * DSTATE];   // 6 KB
    int d = blockIdx.x * 256 + threadIdx.x;   // 0..1023
    int b = blockIdx.z;
    int t0 = blockIdx.y * CHUNK_L;
    int tstart = t0 - LOOKBACK; if (tstart < 0) tstart = 0;
    int lb = t0 - tstart;                     // 0 or 32
    int nv = (lb + CHUNK_L) * (DSTATE / 4);

    const f32x4* gB = (const f32x4*)(Bx + ((size_t)b * SEQ + tstart) * DSTATE);
    const f32x4* gC = (const f32x4*)(Cx + ((size_t)b * SEQ + tstart) * DSTATE);
    for (int i = threadIdx.x; i < nv; i += 256) {
        ((f32x4*)sBx)[i] = gB[i];
        ((f32x4*)sCx)[i] = gC[i];
    }

    float A[DSTATE], h[DSTATE];
    const f32x4* ga = (const f32x4*)(A_log + (size_t)d * DSTATE);
#pragma unroll
    for (int q = 0; q < 4; q++) {
        f32x4 av = ga[q];
#pragma unroll
        for (int c = 0; c < 4; c++) {
            A[q * 4 + c] = expf(av[c]);
            h[q * 4 + c] = 0.0f;
        }
    }
    float Dd = Dvec[d];
    __syncthreads();

    const float* xp = x + (size_t)(b * SEQ + tstart) * DM + d;

    // Phase 1: lookback (no output). lb is 0 or 32; unroll by 4.
    for (int u = 0; u < lb; u += 4) {
        float xv[4];
#pragma unroll
        for (int q = 0; q < 4; q++) xv[q] = xp[(size_t)(u + q) * DM];
#pragma unroll
        for (int q = 0; q < 4; q++) {
            int idx = u + q;
#pragma unroll
            for (int n = 0; n < DSTATE; n++)
                h[n] = h[n] * A[n] + sBx[idx * DSTATE + n] * xv[q];
        }
    }

    // Phase 2: output steps.
    float* gp = gate_out + (size_t)(b * SEQ + t0) * DM + d;
    const float* xp2 = x + (size_t)(b * SEQ + t0) * DM + d;
    for (int u = 0; u < CHUNK_L; u += 4) {
        float xv[4], gv[4], ov[4];
#pragma unroll
        for (int q = 0; q < 4; q++) {
            xv[q] = xp2[(size_t)(u + q) * DM];
            gv[q] = gp [(size_t)(u + q) * DM];
        }
#pragma unroll
        for (int q = 0; q < 4; q++) {
            int idx = lb + u + q;
            float y = 0.0f;
#pragma unroll
            for (int n = 0; n < DSTATE; n++) {
                h[n] = h[n] * A[n] + sBx[idx * DSTATE + n] * xv[q];
                y += h[n] * sCx[idx * DSTATE + n];
            }
            float yv = y + Dd * xv[q];
            ov[q] = gv[q] * yv + (1.0f - gv[q]) * xv[q];
        }
#pragma unroll
        for (int q = 0; q < 4; q++) gp[(size_t)(u + q) * DM] = ov[q];
    }
}

// ---------------------------------------------------------------------------
// K4: LayerNorm over last dim (1024), fp32, IN PLACE on d_out.
// ---------------------------------------------------------------------------
__global__ __launch_bounds__(256) void k_ln(
    float* data, const float* __restrict__ gamma, const float* __restrict__ beta)
{
    int wv = threadIdx.x >> 6, lane = threadIdx.x & 63;
    int row = blockIdx.x * 4 + wv;
    f32x4* rp = (f32x4*)(data + (size_t)row * DM);
    f32x4 v[4];
#pragma unroll
    for (int j = 0; j < 4; j++) v[j] = rp[lane + 64 * j];
    float s = 0.0f, s2 = 0.0f;
#pragma unroll
    for (int j = 0; j < 4; j++)
#pragma unroll
        for (int c = 0; c < 4; c++) { float t = v[j][c]; s += t; s2 += t * t; }
#pragma unroll
    for (int off = 32; off > 0; off >>= 1) {
        s  += __shfl_down(s,  off);
        s2 += __shfl_down(s2, off);
    }
    s = __shfl(s, 0); s2 = __shfl(s2, 0);
    float mu  = s  * (1.0f / DM);
    float var = s2 * (1.0f / DM) - mu * mu;
    float rs  = rsqrtf(var + 1e-5f);
#pragma unroll
    for (int j = 0; j < 4; j++) {
        int c0 = (lane + 64 * j) * 4;
        f32x4 o;
#pragma unroll
        for (int c = 0; c < 4; c++)
            o[c] = (v[j][c] - mu) * rs * gamma[c0 + c] + beta[c0 + c];
        rp[lane + 64 * j] = o;
    }
}

// ---------------------------------------------------------------------------
extern "C" void kernel_launch(void* const* d_in, const int* in_sizes, int n_in,
                              void* d_out, int out_size, void* d_ws, size_t ws_size,
                              hipStream_t stream)
{
    const float* x     = (const float*)d_in[0];
    const float* A_log = (const float*)d_in[1];
    const float* Bw    = (const float*)d_in[2];
    const float* Cw    = (const float*)d_in[3];
    const float* Dv    = (const float*)d_in[4];
    const float* gw    = (const float*)d_in[5];
    const float* gb    = (const float*)d_in[6];
    const float* gam   = (const float*)d_in[7];
    const float* bet   = (const float*)d_in[8];
    float* out = (float*)d_out;   // reused: gate (fp32) -> out_pre -> final

    char* ws = (char*)d_ws;
    u16*   xh  = (u16*)  ws;                             // 32 MB
    u16*   xl  = (u16*)  (ws + (32u << 20));             // 32 MB
    u16*   gwb = (u16*)  (ws + (64u << 20));             // 2 MB
    u16*   bwh = (u16*)  (ws + (66u << 20));             // 32 KB
    u16*   bwl = (u16*)  (ws + (66u << 20) + (32u << 10));
    u16*   cwh = (u16*)  (ws + (66u << 20) + (64u << 10));
    u16*   cwl = (u16*)  (ws + (66u << 20) + (96u << 10));
    float* Bx  = (float*)(ws + (67u << 20));             // 1 MB
    float* Cx  = (float*)(ws + (68u << 20));             // 1 MB

    k_cvt_split<<<ROWS * DM / 4 / 256, 256, 0, stream>>>(x, xh, xl, ROWS * DM / 4);
    k_cvt_w<<<1056, 256, 0, stream>>>(gw, Bw, Cw, gwb, bwh, bwl, cwh, cwl);
    k_bxcx<<<ROWS / 16, 64, 0, stream>>>(xh, xl, bwh, bwl, cwh, cwl, Bx, Cx);
    k_gate<<<dim3(ROWS / BM, DM / BN), 256, 0, stream>>>(xh, gwb, gb, out);
    k_scan<<<dim3(DM / 256, SEQ / CHUNK_L, B_SZ), 256, 0, stream>>>(
        x, A_log, Bx, Cx, Dv, out);
    k_ln<<<ROWS / 4, 256, 0, stream>>>(out, gam, bet);
}